// Round 9
// baseline (126.323 us; speedup 1.0000x reference)
//
#include <hip/hip_runtime.h>
#include <hip/hip_bf16.h>

using short8  = __attribute__((ext_vector_type(8))) short;
using floatx4 = __attribute__((ext_vector_type(4))) float;

#define CC 192
#define CN 4096
#define NHEAD 6
#define DHEAD 32
#define SW(c, n) ((n) ^ (((c) & 7) << 3))

__device__ __forceinline__ float bf2f(short s) {
    return __uint_as_float(((unsigned)(unsigned short)s) << 16);
}
__device__ __forceinline__ short f2bf(float f) {
    __hip_bfloat16 h = __float2bfloat16(f);
    return *(short*)&h;
}

// ---------------- kernel 0: rope cos/sin tables (row- and col-major) ----------------
__global__ void k0_table(float2* __restrict__ tab, float2* __restrict__ tabT) {
    int idx = blockIdx.x * 256 + threadIdx.x;
    if (idx >= CN * 96) return;
    int n = idx / 96, c2 = idx - n * 96;
    int h = n >> 6, w = n & 63;
    int i = (c2 < 48) ? c2 : c2 - 48;
    float pos = (float)((c2 < 48) ? h : w);
    float theta = expf(-(float)i * (9.210340371976184f / 48.0f)); // ln(10000)/48
    float ang = pos * theta;
    float2 v = make_float2(cosf(ang), sinf(ang));
    tab[idx] = v;
    tabT[(long)c2 * CN + n] = v;
}

__global__ void k_zero(float* __restrict__ p, int n) {
    int i = blockIdx.x * 256 + threadIdx.x;
    if (i < n) p[i] = 0.f;
}

// ---------------- kernel 0w: pre-fragment qk_w into bf16 MFMA-B layout ----------------
__global__ void k0_wfrag(const float* __restrict__ qkw, __hip_bfloat16* __restrict__ wfr) {
    int tid = blockIdx.x * 256 + threadIdx.x;     // 0..9215
    if (tid >= 24 * 6 * 64) return;
    int lane = tid & 63;
    int ks = (tid >> 6) % 6;
    int nig = tid / (6 * 64);
    int col = nig * 16 + (lane & 15);
    int k = ks * 32 + (lane >> 4) * 8;
    const float4* src = (const float4*)(qkw + (long)col * CC + k);
    float4 f0 = src[0], f1 = src[1];
    short8 s;
    s[0] = f2bf(f0.x); s[1] = f2bf(f0.y); s[2] = f2bf(f0.z); s[3] = f2bf(f0.w);
    s[4] = f2bf(f1.x); s[5] = f2bf(f1.y); s[6] = f2bf(f1.z); s[7] = f2bf(f1.w);
    *(short8*)&wfr[(long)tid * 8] = s;
}

// ---------------- kernel 1: qk GEMM + elu+1 + FUSED kv/kmean ----------------
// A staged once (S0[64][200]); B per K-step via global_load_lds (S1).
// Epilogue: q -> LDS transpose -> qws;  k -> kT (swizzled, S0) -> rope -> 
// kv partial = kr^T v via MFMA (vT swizzled in S1) -> atomicAdd. No kws.
__global__ __launch_bounds__(256, 3)
void k1_gemm(const float* __restrict__ x, const __hip_bfloat16* __restrict__ wfr,
             const float* __restrict__ qkb, const float2* __restrict__ tabT,
             __hip_bfloat16* __restrict__ qws, __hip_bfloat16* __restrict__ xbf,
             float* __restrict__ kv, float* __restrict__ km)
{
    __shared__ __align__(16) short S0[12800];   // A_full[64][200] -> qT[64][200] -> kT[192][64] swz
    __shared__ __align__(16) short S1[12288];   // B step [24][512] -> vT[192][64] swz

    const int tid  = threadIdx.x;
    const int wid  = tid >> 6, lane = tid & 63;
    const int wm   = wid >> 1, wn = wid & 1;
    const int lrow = lane & 15, l4 = lane >> 4;
    const long rowBase = (long)blockIdx.x * 64;
    const int b   = blockIdx.x >> 6;
    const int nb0 = (blockIdx.x & 63) << 6;     // n position within image

    // ---- stage A_full (x -> bf16) once + emit xbf ----
#pragma unroll
    for (int it = 0; it < 6; ++it) {
        int slot = it * 256 + tid;              // 0..1535 = row(64) x sub(24)
        int row = slot / 24, c0 = (slot % 24) * 8;
        const float4* src = (const float4*)(x + (rowBase + row) * CC + c0);
        float4 f0 = src[0], f1 = src[1];
        short8 s;
        s[0] = f2bf(f0.x); s[1] = f2bf(f0.y); s[2] = f2bf(f0.z); s[3] = f2bf(f0.w);
        s[4] = f2bf(f1.x); s[5] = f2bf(f1.y); s[6] = f2bf(f1.z); s[7] = f2bf(f1.w);
        *(short8*)&S0[row * 200 + c0] = s;
        *(short8*)&xbf[(rowBase + row) * CC + c0] = s;
    }
    __syncthreads();

    floatx4 acc[2][12];
#pragma unroll
    for (int i = 0; i < 2; ++i)
#pragma unroll
        for (int j = 0; j < 12; ++j) acc[i][j] = (floatx4)0.f;

    // ---- K-loop: B DMA -> 24 MFMA ----
    for (int ks = 0; ks < 6; ++ks) {
        if (ks) __syncthreads();                // prev MFMA done reading S1
#pragma unroll
        for (int j = 0; j < 6; ++j) {
            int nig = j * 4 + wid;              // wave-uniform
            const __hip_bfloat16* gp = wfr + ((long)(nig * 6 + ks) * 64 + lane) * 8;
            __builtin_amdgcn_global_load_lds(
                (const __attribute__((address_space(1))) void*)gp,
                (__attribute__((address_space(3))) void*)&S1[nig * 512], 16, 0, 0);
        }
        __syncthreads();                        // DMA drained
        short8 a0 = *(const short8*)&S0[(wm * 32 + lrow) * 200 + ks * 32 + l4 * 8];
        short8 a1 = *(const short8*)&S0[(wm * 32 + 16 + lrow) * 200 + ks * 32 + l4 * 8];
#pragma unroll
        for (int ni = 0; ni < 12; ++ni) {
            short8 bf = *(const short8*)&S1[(wn * 12 + ni) * 512 + lane * 8];
            acc[0][ni] = __builtin_amdgcn_mfma_f32_16x16x32_bf16(a0, bf, acc[0][ni], 0, 0, 0);
            acc[1][ni] = __builtin_amdgcn_mfma_f32_16x16x32_bf16(a1, bf, acc[1][ni], 0, 0, 0);
        }
    }
    __syncthreads();                            // S1 reads done

    // ---- build vT (swizzled) in S1 from A_full ----
#pragma unroll
    for (int it = 0; it < 6; ++it) {
        int slot = it * 256 + tid;
        int row = slot / 24, c0 = (slot % 24) * 8;
        short8 v = *(const short8*)&S0[row * 200 + c0];
#pragma unroll
        for (int j = 0; j < 8; ++j) {
            int c = c0 + j;
            S1[c * 64 + SW(c, row)] = v[j];
        }
    }
    __syncthreads();                            // vT stable; A_full reads done

    // ---- ph0: q epilogue -> S0[64][200] ----
    if (wn == 0) {
#pragma unroll
        for (int ni = 0; ni < 12; ++ni) {
            int col = ni * 16 + lrow;
            float bias = qkb[col];
#pragma unroll
            for (int mi = 0; mi < 2; ++mi)
#pragma unroll
                for (int r = 0; r < 4; ++r) {
                    int rowl = wm * 32 + mi * 16 + l4 * 4 + r;
                    float v = acc[mi][ni][r] + bias;
                    v = (v > 0.f) ? (v + 1.f) : expf(v);
                    S0[rowl * 200 + col] = f2bf(v);
                }
        }
    }
    __syncthreads();
#pragma unroll
    for (int it = 0; it < 6; ++it) {            // coalesced qws store
        int slot = it * 256 + tid;
        int row = slot / 24, c0 = (slot % 24) * 8;
        short8 v = *(const short8*)&S0[row * 200 + c0];
        *(short8*)&qws[(rowBase + row) * CC + c0] = v;
    }
    __syncthreads();                            // S0 reads done

    // ---- ph1: k -> kT (swizzled) + in-register kmean ----
    if (wn == 1) {
#pragma unroll
        for (int ni = 0; ni < 12; ++ni) {
            int col = ni * 16 + lrow;
            float bias = qkb[CC + col];
            float kms = 0.f;
#pragma unroll
            for (int mi = 0; mi < 2; ++mi)
#pragma unroll
                for (int r = 0; r < 4; ++r) {
                    int rowl = wm * 32 + mi * 16 + l4 * 4 + r;
                    float v = acc[mi][ni][r] + bias;
                    v = (v > 0.f) ? (v + 1.f) : expf(v);
                    kms += v;
                    S0[col * 64 + SW(col, rowl)] = f2bf(v);
                }
            kms += __shfl_xor(kms, 16);
            kms += __shfl_xor(kms, 32);
            if (lane < 16) atomicAdd(&km[b * CC + col], kms * (1.f / 4096.f));
        }
    }
    __syncthreads();                            // kT visible

    // ---- rope in place on kT (pair rows 2c2, 2c2+1) via tabT ----
    if (tid < 192) {
        int c2 = tid >> 1, ns = tid & 1;
        int re_ = 2 * c2, ro_ = re_ + 1;
        int se = (re_ & 7) << 3;
#pragma unroll
        for (int mb = 0; mb < 4; ++mb) {
            int n0 = ns * 32 + mb * 8;
            short* pe = &S0[re_ * 64 + (n0 ^ se)];
            short* po = &S0[ro_ * 64 + (n0 ^ se ^ 8)];
            short8 ke = *(short8*)pe, ko = *(short8*)po;
            const float4* tp = (const float4*)&tabT[(long)c2 * CN + nb0 + n0];
            float4 t0 = tp[0], t1 = tp[1], t2 = tp[2], t3 = tp[3];
            short8 oe, oo;
            float e, o;
            e = bf2f(ke[0]); o = bf2f(ko[0]); oe[0] = f2bf(e*t0.x - o*t0.y); oo[0] = f2bf(e*t0.y + o*t0.x);
            e = bf2f(ke[1]); o = bf2f(ko[1]); oe[1] = f2bf(e*t0.z - o*t0.w); oo[1] = f2bf(e*t0.w + o*t0.z);
            e = bf2f(ke[2]); o = bf2f(ko[2]); oe[2] = f2bf(e*t1.x - o*t1.y); oo[2] = f2bf(e*t1.y + o*t1.x);
            e = bf2f(ke[3]); o = bf2f(ko[3]); oe[3] = f2bf(e*t1.z - o*t1.w); oo[3] = f2bf(e*t1.w + o*t1.z);
            e = bf2f(ke[4]); o = bf2f(ko[4]); oe[4] = f2bf(e*t2.x - o*t2.y); oo[4] = f2bf(e*t2.y + o*t2.x);
            e = bf2f(ke[5]); o = bf2f(ko[5]); oe[5] = f2bf(e*t2.z - o*t2.w); oo[5] = f2bf(e*t2.w + o*t2.z);
            e = bf2f(ke[6]); o = bf2f(ko[6]); oe[6] = f2bf(e*t3.x - o*t3.y); oo[6] = f2bf(e*t3.y + o*t3.x);
            e = bf2f(ke[7]); o = bf2f(ko[7]); oe[7] = f2bf(e*t3.z - o*t3.w); oo[7] = f2bf(e*t3.w + o*t3.z);
            *(short8*)pe = oe;
            *(short8*)po = oo;
        }
    }
    __syncthreads();

    // ---- kv partial = kr^T v via MFMA + atomics ----
    {
        const int dt = wid >> 1, et = wid & 1;
        float* kvb = kv + (long)b * NHEAD * DHEAD * DHEAD;
        const int e = et * 16 + lrow;
#pragma unroll
        for (int hd = 0; hd < NHEAD; ++hd) {
            int ca = hd * 32 + dt * 16 + lrow;  // kr row (d)
            int cb = hd * 32 + e;               // v row (e)
            floatx4 a6 = (floatx4)0.f;
#pragma unroll
            for (int kt = 0; kt < 2; ++kt) {
                int n0 = kt * 32 + l4 * 8;
                short8 af = *(const short8*)&S0[ca * 64 + SW(ca, n0)];
                short8 bf = *(const short8*)&S1[cb * 64 + SW(cb, n0)];
                a6 = __builtin_amdgcn_mfma_f32_16x16x32_bf16(af, bf, a6, 0, 0, 0);
            }
#pragma unroll
            for (int rr = 0; rr < 4; ++rr) {
                int d = dt * 16 + l4 * 4 + rr;
                atomicAdd(&kvb[(hd * DHEAD + d) * DHEAD + e], a6[rr] * (1.f / 4096.f));
            }
        }
    }
}

// ---------------- kernel 3: out = (q_rope @ kv) * z + lepe ----------------
__global__ __launch_bounds__(256)
void k3_out(const __hip_bfloat16* __restrict__ qws, const __hip_bfloat16* __restrict__ xbf,
            const float2* __restrict__ tab, const float* __restrict__ kv,
            const float* __restrict__ kmean, const float* __restrict__ lw,
            const float* __restrict__ lb, float* __restrict__ out)
{
    int raw = blockIdx.x;
    int bid = (raw & 7) * 128 + (raw >> 3);   // 8 XCDs x 128 contiguous blocks
    int b = bid >> 6, h = bid & 63;
    int tid = threadIdx.x;
    int wave = tid >> 6, lane = tid & 63, lrow = lane & 15, l4 = lane >> 4;

    __shared__ __align__(16) __hip_bfloat16 qa[64][104];        // q_rope, then attn*z
    __shared__ __align__(16) __hip_bfloat16 kvt[NHEAD][32][36]; // [hd][e][d]
    __shared__ __align__(16) float lwT[9][192];                 // [tap][ch]
    __shared__ float lb_lds[CC];
    __shared__ float km_lds[CC];
    __shared__ float zden[64][8];

    const long nbase = (long)b * CN + h * 64;

    const float* kvsrc = kv + (long)b * NHEAD * DHEAD * DHEAD;
    for (int i = tid; i < NHEAD * DHEAD * DHEAD; i += 256) {
        int hd = i >> 10, d = (i >> 5) & 31, e = i & 31;
        kvt[hd][e][d] = __float2bfloat16(kvsrc[i]);
    }
    if (tid < CC) { km_lds[tid] = kmean[b * CC + tid]; lb_lds[tid] = lb[tid]; }
    for (int i = tid; i < CC * 9; i += 256) {
        int c = i / 9, tap = i - c * 9;
        lwT[tap][c] = lw[i];
    }
    __syncthreads();

#pragma unroll
    for (int half = 0; half < 2; ++half) {
#pragma unroll
        for (int it = 0; it < 3; ++it) {
            int slot = it * 256 + tid;          // 0..767 = w(64) x sub(12)
            int w = slot / 12;
            int sub = slot - w * 12;
            int c0 = half * 96 + sub * 8;
            short8 qv = *(const short8*)&qws[(nbase + w) * CC + c0];
            float q[8];
#pragma unroll
            for (int j = 0; j < 8; ++j) q[j] = bf2f(qv[j]);
            float p = 0.f;
#pragma unroll
            for (int j = 0; j < 8; ++j) p += q[j] * km_lds[c0 + j];
            p += __shfl_xor(p, 1);
            p += __shfl_xor(p, 2);
            if ((sub & 3) == 0) zden[w][half * 3 + (sub >> 2)] = p;
            int n = h * 64 + w;
            const float4* tp = (const float4*)&tab[(long)n * 96 + (c0 >> 1)];
            float4 t0 = tp[0], t1 = tp[1];
            short8 qr;
            qr[0] = f2bf(q[0]*t0.x - q[1]*t0.y);  qr[1] = f2bf(q[0]*t0.y + q[1]*t0.x);
            qr[2] = f2bf(q[2]*t0.z - q[3]*t0.w);  qr[3] = f2bf(q[2]*t0.w + q[3]*t0.z);
            qr[4] = f2bf(q[4]*t1.x - q[5]*t1.y);  qr[5] = f2bf(q[4]*t1.y + q[5]*t1.x);
            qr[6] = f2bf(q[6]*t1.z - q[7]*t1.w);  qr[7] = f2bf(q[6]*t1.w + q[7]*t1.z);
            *(short8*)&qa[w][sub * 8] = qr;
        }
        __syncthreads();

        const int rt = wave;
        const int wbase = rt * 16 + l4 * 4;
#pragma unroll
        for (int hl = 0; hl < 3; ++hl) {
            int hd = half * 3 + hl;
            short8 a = *(const short8*)&qa[rt * 16 + lrow][hl * 32 + l4 * 8];
            float zv[4];
#pragma unroll
            for (int r = 0; r < 4; ++r) zv[r] = 1.f / (zden[wbase + r][hd] + 1e-6f);
#pragma unroll
            for (int nt = 0; nt < 2; ++nt) {
                short8 bfr = *(const short8*)&kvt[hd][nt * 16 + lrow][l4 * 8];
                floatx4 acc = __builtin_amdgcn_mfma_f32_16x16x32_bf16(a, bfr, (floatx4)0.f, 0, 0, 0);
                int col_l = hl * 32 + nt * 16 + lrow;
#pragma unroll
                for (int r = 0; r < 4; ++r)
                    qa[wbase + r][col_l] = __float2bfloat16(acc[r] * zv[r]);
            }
        }
        __syncthreads();

#pragma unroll
        for (int it = 0; it < 3; ++it) {
            int slot = it * 256 + tid;          // 0..767 = w(64) x g(12)
            int w = slot / 12;
            int g = slot - w * 12;
            int c0g = g * 8;
            int c0 = half * 96 + c0g;
            float vals[8];
#pragma unroll
            for (int j = 0; j < 8; ++j) vals[j] = lb_lds[c0 + j];
#pragma unroll
            for (int dy = 0; dy < 3; ++dy) {
                int hy = h + dy - 1;
                if (hy < 0 || hy > 63) continue;
                const short* base = (const short*)xbf + (((long)b * 64 + hy) * 64) * CC + c0;
#pragma unroll
                for (int dx = 0; dx < 3; ++dx) {
                    int wx = w + dx - 1;
                    if (wx < 0 || wx > 63) continue;
                    short8 xv = *(const short8*)&base[(long)wx * CC];
                    const float4* wt4 = (const float4*)&lwT[dy * 3 + dx][c0];
                    float4 wa = wt4[0], wb = wt4[1];
                    vals[0] += bf2f(xv[0]) * wa.x;  vals[1] += bf2f(xv[1]) * wa.y;
                    vals[2] += bf2f(xv[2]) * wa.z;  vals[3] += bf2f(xv[3]) * wa.w;
                    vals[4] += bf2f(xv[4]) * wb.x;  vals[5] += bf2f(xv[5]) * wb.y;
                    vals[6] += bf2f(xv[6]) * wb.z;  vals[7] += bf2f(xv[7]) * wb.w;
                }
            }
            short8 at = *(const short8*)&qa[w][c0g];
#pragma unroll
            for (int j = 0; j < 8; ++j) vals[j] += bf2f(at[j]);
            float4 o0, o1;
            o0.x = vals[0]; o0.y = vals[1]; o0.z = vals[2]; o0.w = vals[3];
            o1.x = vals[4]; o1.y = vals[5]; o1.z = vals[6]; o1.w = vals[7];
            float* op = &out[(nbase + w) * CC + c0];
            *(float4*)op = o0;
            *(float4*)(op + 4) = o1;
        }
        __syncthreads();
    }
}

extern "C" void kernel_launch(void* const* d_in, const int* in_sizes, int n_in,
                              void* d_out, int out_size, void* d_ws, size_t ws_size,
                              hipStream_t stream)
{
    const float* x   = (const float*)d_in[0];
    const float* qkw = (const float*)d_in[1];
    const float* qkb = (const float*)d_in[2];
    const float* lw  = (const float*)d_in[3];
    const float* lb  = (const float*)d_in[4];
    float* out = (float*)d_out;

    char* ws = (char*)d_ws;
    float2* tab  = (float2*)ws;                ws += (size_t)CN * 96 * sizeof(float2);
    float2* tabT = (float2*)ws;                ws += (size_t)96 * CN * sizeof(float2);
    __hip_bfloat16* qws = (__hip_bfloat16*)ws; ws += (size_t)16 * CN * CC * 2;
    __hip_bfloat16* xbf = (__hip_bfloat16*)ws; ws += (size_t)16 * CN * CC * 2;
    __hip_bfloat16* wfr = (__hip_bfloat16*)ws; ws += (size_t)24 * 6 * 64 * 8 * 2;
    float* kv = (float*)ws;                    ws += (size_t)16 * NHEAD * DHEAD * DHEAD * 4;
    float* km = (float*)ws;                    ws += (size_t)16 * NHEAD * DHEAD * 4;

    const int nzero = 16 * NHEAD * DHEAD * DHEAD + 16 * NHEAD * DHEAD;
    k_zero<<<(nzero + 255) / 256, 256, 0, stream>>>(kv, nzero);
    k0_table<<<(CN * 96 + 255) / 256, 256, 0, stream>>>(tab, tabT);
    k0_wfrag<<<36, 256, 0, stream>>>(qkw, wfr);
    k1_gemm<<<1024, 256, 0, stream>>>(x, wfr, qkb, tabT, qws, xbf, kv, km);
    k3_out<<<16 * 64, 256, 0, stream>>>(qws, xbf, tab, kv, km, lw, lb, out);
}

// Round 10
// 115.359 us; speedup vs baseline: 1.0950x; 1.0950x over previous
//
#include <hip/hip_runtime.h>
#include <hip/hip_bf16.h>

using short8  = __attribute__((ext_vector_type(8))) short;
using floatx4 = __attribute__((ext_vector_type(4))) float;

#define CC 192
#define CN 4096
#define NHEAD 6
#define DHEAD 32
#define NZERO (16 * NHEAD * DHEAD * DHEAD + 16 * NHEAD * DHEAD)
#define ZBLK ((NZERO + 255) / 256)
#define TBLK ((CN * 96 + 255) / 256)

__device__ __forceinline__ float bf2f(short s) {
    return __uint_as_float(((unsigned)(unsigned short)s) << 16);
}
__device__ __forceinline__ short f2bf(float f) {
    __hip_bfloat16 h = __float2bfloat16(f);
    return *(short*)&h;
}

// ---------------- kernel 0: merged setup (zero kv/km, packed rope table, w-fragments) ----------------
__global__ void k0_all(float* __restrict__ zp, unsigned* __restrict__ tabp,
                       const float* __restrict__ qkw, __hip_bfloat16* __restrict__ wfr)
{
    int bid = blockIdx.x;
    if (bid < ZBLK) {
        int i = bid * 256 + threadIdx.x;
        if (i < NZERO) zp[i] = 0.f;
    } else if (bid < ZBLK + TBLK) {
        int idx = (bid - ZBLK) * 256 + threadIdx.x;
        if (idx >= CN * 96) return;
        int n = idx / 96, c2 = idx - n * 96;
        int h = n >> 6, w = n & 63;
        int i = (c2 < 48) ? c2 : c2 - 48;
        float pos = (float)((c2 < 48) ? h : w);
        float theta = expf(-(float)i * (9.210340371976184f / 48.0f)); // ln(10000)/48
        float ang = pos * theta;
        unsigned c = (unsigned)(unsigned short)f2bf(cosf(ang));
        unsigned s = (unsigned)(unsigned short)f2bf(sinf(ang));
        tabp[idx] = c | (s << 16);
    } else {
        // wfr[((nig*6+ks)*64 + lane)*8 + j] = bf16(qkw[col][k]),
        // col = nig*16 + (lane&15), k = ks*32 + (lane>>4)*8 + j
        int tid = (bid - ZBLK - TBLK) * 256 + threadIdx.x;
        if (tid >= 24 * 6 * 64) return;
        int lane = tid & 63;
        int ks = (tid >> 6) % 6;
        int nig = tid / (6 * 64);
        int col = nig * 16 + (lane & 15);
        int k = ks * 32 + (lane >> 4) * 8;
        const float4* src = (const float4*)(qkw + (long)col * CC + k);
        float4 f0 = src[0], f1 = src[1];
        short8 s;
        s[0] = f2bf(f0.x); s[1] = f2bf(f0.y); s[2] = f2bf(f0.z); s[3] = f2bf(f0.w);
        s[4] = f2bf(f1.x); s[5] = f2bf(f1.y); s[6] = f2bf(f1.z); s[7] = f2bf(f1.w);
        *(short8*)&wfr[(long)tid * 8] = s;
    }
}

// ---------------- kernel 1: qk GEMM + elu+1 -> q,k bf16 ; also emits xbf ----------------
// Round-7 proven structure: per-step LDS staging, B staged as pure bf16 copy
// from wfr in fragment order (zero conversions, conflict-free LDS access).
#define LDSP 40
__global__ __launch_bounds__(512)
void k1_gemm(const float* __restrict__ x, const __hip_bfloat16* __restrict__ wfr,
             const float* __restrict__ qkb,
             __hip_bfloat16* __restrict__ qws, __hip_bfloat16* __restrict__ kws,
             __hip_bfloat16* __restrict__ xbf)
{
    __shared__ __align__(16) __hip_bfloat16 A_lds[128 * LDSP];
    __shared__ __align__(16) __hip_bfloat16 B_lds[24 * 512];   // [nig][lane*8], one K-step

    const int tid  = threadIdx.x;
    const int wid  = tid >> 6, lane = tid & 63;
    const int wm   = wid >> 1, wn = wid & 1;
    const int lrow = lane & 15;
    const int l4   = lane >> 4;
    const int lk   = l4 * 8;
    const long rowBase = (long)blockIdx.x * 128;

    const int ar = tid >> 2, acc_c = (tid & 3) * 8;   // A-stage coords

    floatx4 acc[2][12];
#pragma unroll
    for (int i = 0; i < 2; ++i)
#pragma unroll
        for (int j = 0; j < 12; ++j) acc[i][j] = (floatx4)0.f;

    for (int ks = 0; ks < 6; ++ks) {
        const int k0 = ks * 32;

        // ---- issue global loads for this step's staging (before barrier:
        //      overlaps previous step's compute) ----
        short8 bstage[3];
#pragma unroll
        for (int j = 0; j < 3; ++j) {
            int s = j * 512 + tid;            // 0..1535 = nig(24) x lane(64)
            int nig = s >> 6, ln = s & 63;
            bstage[j] = *(const short8*)&wfr[((long)(nig * 6 + ks) * 64 + ln) * 8];
        }
        const float4* asrc = (const float4*)(x + (rowBase + ar) * CC + k0 + acc_c);
        float4 f0 = asrc[0], f1 = asrc[1];
        short8 as;
        as[0] = f2bf(f0.x); as[1] = f2bf(f0.y); as[2] = f2bf(f0.z); as[3] = f2bf(f0.w);
        as[4] = f2bf(f1.x); as[5] = f2bf(f1.y); as[6] = f2bf(f1.z); as[7] = f2bf(f1.w);

        if (ks) __syncthreads();              // prev-step LDS reads done

        *(short8*)&A_lds[ar * LDSP + acc_c] = as;
        *(short8*)&xbf[(rowBase + ar) * CC + k0 + acc_c] = as;
#pragma unroll
        for (int j = 0; j < 3; ++j) {
            int s = j * 512 + tid;
            *(short8*)&B_lds[s * 8] = bstage[j];
        }
        __syncthreads();

        // ---- compute: 24 MFMA per wave ----
        short8 a0 = *(const short8*)&A_lds[(wm * 32 + lrow) * LDSP + lk];
        short8 a1 = *(const short8*)&A_lds[(wm * 32 + 16 + lrow) * LDSP + lk];
#pragma unroll
        for (int ni = 0; ni < 12; ++ni) {
            short8 bf = *(const short8*)&B_lds[(wn * 12 + ni) * 512 + lane * 8];
            acc[0][ni] = __builtin_amdgcn_mfma_f32_16x16x32_bf16(a0, bf, acc[0][ni], 0, 0, 0);
            acc[1][ni] = __builtin_amdgcn_mfma_f32_16x16x32_bf16(a1, bf, acc[1][ni], 0, 0, 0);
        }
    }

    // ---- epilogue: +bias, elu+1, write bf16 ----
    __hip_bfloat16* dstbase = wn ? kws : qws;
#pragma unroll
    for (int ni = 0; ni < 12; ++ni) {
        int col_l = ni * 16 + lrow;
        float bias = qkb[wn * 192 + col_l];
#pragma unroll
        for (int mi = 0; mi < 2; ++mi) {
#pragma unroll
            for (int r = 0; r < 4; ++r) {
                int rowl = wm * 32 + mi * 16 + l4 * 4 + r;
                long rowg = rowBase + rowl;
                float v = acc[mi][ni][r] + bias;
                v = (v > 0.f) ? (v + 1.f) : expf(v);
                dstbase[rowg * CC + col_l] = __float2bfloat16(v);
            }
        }
    }
}

// ---------------- kernel 2: kv = (1/4096) k_rope^T v ; kmean ----------------
// Slimmed: 64-row batches, 16 chunks -> grid 1536, LDS 18.6KB (8 blocks/CU cap).
__global__ __launch_bounds__(256)
void k2_kv(const __hip_bfloat16* __restrict__ kws, const __hip_bfloat16* __restrict__ xbf,
           const unsigned* __restrict__ tabp, float* __restrict__ kv, float* __restrict__ kmean)
{
    int bid = blockIdx.x;
    int chunk = bid & 15;
    int hd = (bid >> 4) % NHEAD;
    int b = bid / (16 * NHEAD);
    int tid = threadIdx.x;

    __shared__ __align__(16) float kr_s[64][36];
    __shared__ __align__(16) float v_s[64][36];
    __shared__ float km_s[32];

    if (tid < 32) km_s[tid] = 0.f;

    const int e_g = tid & 31, g = tid >> 5, d4 = g * 4;
    const int krow = tid >> 2, kq = tid & 3;   // 64 rows/pass

    float acc0 = 0.f, acc1 = 0.f, acc2 = 0.f, acc3 = 0.f;
    float msum[8];
#pragma unroll
    for (int j = 0; j < 8; ++j) msum[j] = 0.f;

    const int n0 = chunk * 256;
    const long rb = (long)b * CN;

    for (int batch = 0; batch < 4; ++batch) {
        const int nb = n0 + batch * 64;
        if (batch) __syncthreads();
        // --- load+rope k: 64 rows ---
        {
            int r = krow;
            int n = nb + r;
            short8 kq8 = *(const short8*)&kws[(rb + n) * CC + hd * DHEAD + kq * 8];
            float kf[8];
#pragma unroll
            for (int j = 0; j < 8; ++j) { kf[j] = bf2f(kq8[j]); msum[j] += kf[j]; }
            uint4 u = *(const uint4*)&tabp[(long)n * 96 + hd * 16 + kq * 4];
            float4 t0, t1;
            t0.x = bf2f((short)(u.x & 0xffff)); t0.y = bf2f((short)(u.x >> 16));
            t0.z = bf2f((short)(u.y & 0xffff)); t0.w = bf2f((short)(u.y >> 16));
            t1.x = bf2f((short)(u.z & 0xffff)); t1.y = bf2f((short)(u.z >> 16));
            t1.z = bf2f((short)(u.w & 0xffff)); t1.w = bf2f((short)(u.w >> 16));
            float4 r0, r1;
            r0.x = kf[0]*t0.x - kf[1]*t0.y;  r0.y = kf[0]*t0.y + kf[1]*t0.x;
            r0.z = kf[2]*t0.z - kf[3]*t0.w;  r0.w = kf[2]*t0.w + kf[3]*t0.z;
            r1.x = kf[4]*t1.x - kf[5]*t1.y;  r1.y = kf[4]*t1.y + kf[5]*t1.x;
            r1.z = kf[6]*t1.z - kf[7]*t1.w;  r1.w = kf[6]*t1.w + kf[7]*t1.z;
            *(float4*)&kr_s[r][kq * 8]     = r0;
            *(float4*)&kr_s[r][kq * 8 + 4] = r1;
        }
        // --- load v (bf16): 64 rows ---
        {
            int r = krow;
            short8 v8 = *(const short8*)&xbf[(rb + nb + r) * CC + hd * DHEAD + kq * 8];
            float4 va, vb;
            va.x = bf2f(v8[0]); va.y = bf2f(v8[1]); va.z = bf2f(v8[2]); va.w = bf2f(v8[3]);
            vb.x = bf2f(v8[4]); vb.y = bf2f(v8[5]); vb.z = bf2f(v8[6]); vb.w = bf2f(v8[7]);
            *(float4*)&v_s[r][kq * 8]     = va;
            *(float4*)&v_s[r][kq * 8 + 4] = vb;
        }
        __syncthreads();
#pragma unroll 8
        for (int r = 0; r < 64; ++r) {
            float4 k4 = *(const float4*)&kr_s[r][d4];
            float v1 = v_s[r][e_g];
            acc0 += k4.x * v1; acc1 += k4.y * v1; acc2 += k4.z * v1; acc3 += k4.w * v1;
        }
    }
    const float s = 1.f / 4096.f;
    float* kvb = kv + (long)(b * NHEAD + hd) * DHEAD * DHEAD;
    atomicAdd(&kvb[(d4 + 0) * DHEAD + e_g], acc0 * s);
    atomicAdd(&kvb[(d4 + 1) * DHEAD + e_g], acc1 * s);
    atomicAdd(&kvb[(d4 + 2) * DHEAD + e_g], acc2 * s);
    atomicAdd(&kvb[(d4 + 3) * DHEAD + e_g], acc3 * s);
    __syncthreads();
#pragma unroll
    for (int j = 0; j < 8; ++j) atomicAdd(&km_s[kq * 8 + j], msum[j]);
    __syncthreads();
    if (tid < 32) atomicAdd(&kmean[(b * NHEAD + hd) * DHEAD + tid], km_s[tid] * s);
}

// ---------------- kernel 3: out = (q_rope @ kv) * z + lepe ----------------
// XCD-swizzled blocks. Per half (96 ch): phase1 q load/rope/zden ->
// phase2 MFMA+z, attn bf16 into qa in place -> phase3 parallel LePE.
__global__ __launch_bounds__(256)
void k3_out(const __hip_bfloat16* __restrict__ qws, const __hip_bfloat16* __restrict__ xbf,
            const unsigned* __restrict__ tabp, const float* __restrict__ kv,
            const float* __restrict__ kmean, const float* __restrict__ lw,
            const float* __restrict__ lb, float* __restrict__ out)
{
    int raw = blockIdx.x;
    int bid = (raw & 7) * 128 + (raw >> 3);   // 8 XCDs x 128 contiguous blocks
    int b = bid >> 6, h = bid & 63;
    int tid = threadIdx.x;
    int wave = tid >> 6, lane = tid & 63, lrow = lane & 15, l4 = lane >> 4;

    __shared__ __align__(16) __hip_bfloat16 qa[64][104];        // q_rope, then attn*z
    __shared__ __align__(16) __hip_bfloat16 kvt[NHEAD][32][36]; // [hd][e][d]
    __shared__ __align__(16) float lwT[9][192];                 // [tap][ch]
    __shared__ float lb_lds[CC];
    __shared__ float km_lds[CC];
    __shared__ float zden[64][8];

    const long nbase = (long)b * CN + h * 64;

    // ---- phase 0: stage kv^T (bf16), kmean, lb, transposed lw ----
    const float* kvsrc = kv + (long)b * NHEAD * DHEAD * DHEAD;
    for (int i = tid; i < NHEAD * DHEAD * DHEAD; i += 256) {
        int hd = i >> 10, d = (i >> 5) & 31, e = i & 31;
        kvt[hd][e][d] = __float2bfloat16(kvsrc[i]);
    }
    if (tid < CC) { km_lds[tid] = kmean[b * CC + tid]; lb_lds[tid] = lb[tid]; }
    for (int i = tid; i < CC * 9; i += 256) {
        int c = i / 9, tap = i - c * 9;
        lwT[tap][c] = lw[i];
    }
    __syncthreads();

#pragma unroll
    for (int half = 0; half < 2; ++half) {
        // ---- phase 1: q load (coalesced), rope, per-head z dots ----
#pragma unroll
        for (int it = 0; it < 3; ++it) {
            int slot = it * 256 + tid;          // 0..767 = w(64) x sub(12)
            int w = slot / 12;
            int sub = slot - w * 12;
            int c0 = half * 96 + sub * 8;
            short8 qv = *(const short8*)&qws[(nbase + w) * CC + c0];
            float q[8];
#pragma unroll
            for (int j = 0; j < 8; ++j) q[j] = bf2f(qv[j]);
            float p = 0.f;
#pragma unroll
            for (int j = 0; j < 8; ++j) p += q[j] * km_lds[c0 + j];
            p += __shfl_xor(p, 1);
            p += __shfl_xor(p, 2);
            if ((sub & 3) == 0) zden[w][half * 3 + (sub >> 2)] = p;
            int n = h * 64 + w;
            uint4 u = *(const uint4*)&tabp[(long)n * 96 + (c0 >> 1)];
            float4 t0, t1;
            t0.x = bf2f((short)(u.x & 0xffff)); t0.y = bf2f((short)(u.x >> 16));
            t0.z = bf2f((short)(u.y & 0xffff)); t0.w = bf2f((short)(u.y >> 16));
            t1.x = bf2f((short)(u.z & 0xffff)); t1.y = bf2f((short)(u.z >> 16));
            t1.z = bf2f((short)(u.w & 0xffff)); t1.w = bf2f((short)(u.w >> 16));
            short8 qr;
            qr[0] = f2bf(q[0]*t0.x - q[1]*t0.y);  qr[1] = f2bf(q[0]*t0.y + q[1]*t0.x);
            qr[2] = f2bf(q[2]*t0.z - q[3]*t0.w);  qr[3] = f2bf(q[2]*t0.w + q[3]*t0.z);
            qr[4] = f2bf(q[4]*t1.x - q[5]*t1.y);  qr[5] = f2bf(q[4]*t1.y + q[5]*t1.x);
            qr[6] = f2bf(q[6]*t1.z - q[7]*t1.w);  qr[7] = f2bf(q[6]*t1.w + q[7]*t1.z);
            *(short8*)&qa[w][sub * 8] = qr;
        }
        __syncthreads();

        // ---- phase 2: MFMA matvec, scale by z, attn bf16 in place ----
        const int rt = wave;                   // each wave owns rows [rt*16, rt*16+16)
        const int wbase = rt * 16 + l4 * 4;
#pragma unroll
        for (int hl = 0; hl < 3; ++hl) {
            int hd = half * 3 + hl;
            short8 a = *(const short8*)&qa[rt * 16 + lrow][hl * 32 + l4 * 8];
            float zv[4];
#pragma unroll
            for (int r = 0; r < 4; ++r) zv[r] = 1.f / (zden[wbase + r][hd] + 1e-6f);
#pragma unroll
            for (int nt = 0; nt < 2; ++nt) {
                short8 bfr = *(const short8*)&kvt[hd][nt * 16 + lrow][l4 * 8];
                floatx4 acc = __builtin_amdgcn_mfma_f32_16x16x32_bf16(a, bfr, (floatx4)0.f, 0, 0, 0);
                int col_l = hl * 32 + nt * 16 + lrow;   // within half
#pragma unroll
                for (int r = 0; r < 4; ++r)
                    qa[wbase + r][col_l] = __float2bfloat16(acc[r] * zv[r]);
            }
        }
        __syncthreads();

        // ---- phase 3: parallel LePE (coalesced) + add attn + store ----
#pragma unroll
        for (int it = 0; it < 3; ++it) {
            int slot = it * 256 + tid;          // 0..767 = w(64) x g(12)
            int w = slot / 12;
            int g = slot - w * 12;
            int c0g = g * 8;
            int c0 = half * 96 + c0g;
            float vals[8];
#pragma unroll
            for (int j = 0; j < 8; ++j) vals[j] = lb_lds[c0 + j];
#pragma unroll
            for (int dy = 0; dy < 3; ++dy) {
                int hy = h + dy - 1;
                if (hy < 0 || hy > 63) continue;
                const short* base = (const short*)xbf + (((long)b * 64 + hy) * 64) * CC + c0;
#pragma unroll
                for (int dx = 0; dx < 3; ++dx) {
                    int wx = w + dx - 1;
                    if (wx < 0 || wx > 63) continue;
                    short8 xv = *(const short8*)&base[(long)wx * CC];
                    const float4* wt4 = (const float4*)&lwT[dy * 3 + dx][c0];
                    float4 wa = wt4[0], wb = wt4[1];
                    vals[0] += bf2f(xv[0]) * wa.x;  vals[1] += bf2f(xv[1]) * wa.y;
                    vals[2] += bf2f(xv[2]) * wa.z;  vals[3] += bf2f(xv[3]) * wa.w;
                    vals[4] += bf2f(xv[4]) * wb.x;  vals[5] += bf2f(xv[5]) * wb.y;
                    vals[6] += bf2f(xv[6]) * wb.z;  vals[7] += bf2f(xv[7]) * wb.w;
                }
            }
            short8 at = *(const short8*)&qa[w][c0g];
#pragma unroll
            for (int j = 0; j < 8; ++j) vals[j] += bf2f(at[j]);
            float4 o0, o1;
            o0.x = vals[0]; o0.y = vals[1]; o0.z = vals[2]; o0.w = vals[3];
            o1.x = vals[4]; o1.y = vals[5]; o1.z = vals[6]; o1.w = vals[7];
            float* op = &out[(nbase + w) * CC + c0];
            *(float4*)op = o0;
            *(float4*)(op + 4) = o1;
        }
        __syncthreads();   // qa/zden reuse in next half
    }
}

extern "C" void kernel_launch(void* const* d_in, const int* in_sizes, int n_in,
                              void* d_out, int out_size, void* d_ws, size_t ws_size,
                              hipStream_t stream)
{
    const float* x   = (const float*)d_in[0];
    const float* qkw = (const float*)d_in[1];
    const float* qkb = (const float*)d_in[2];
    const float* lw  = (const float*)d_in[3];
    const float* lb  = (const float*)d_in[4];
    float* out = (float*)d_out;

    char* ws = (char*)d_ws;
    unsigned* tabp = (unsigned*)ws;            ws += (size_t)CN * 96 * 4;
    __hip_bfloat16* qws = (__hip_bfloat16*)ws; ws += (size_t)16 * CN * CC * 2;
    __hip_bfloat16* kws = (__hip_bfloat16*)ws; ws += (size_t)16 * CN * CC * 2;
    __hip_bfloat16* xbf = (__hip_bfloat16*)ws; ws += (size_t)16 * CN * CC * 2;
    __hip_bfloat16* wfr = (__hip_bfloat16*)ws; ws += (size_t)24 * 6 * 64 * 8 * 2;
    float* kv = (float*)ws;                    ws += (size_t)16 * NHEAD * DHEAD * DHEAD * 4;
    float* km = (float*)ws;                    ws += (size_t)16 * NHEAD * DHEAD * 4;

    const int wblk = (24 * 6 * 64 + 255) / 256;
    k0_all<<<ZBLK + TBLK + wblk, 256, 0, stream>>>(kv, tabp, qkw, wfr);
    k1_gemm<<<512, 512, 0, stream>>>(x, wfr, qkb, qws, kws, xbf);
    k2_kv<<<16 * NHEAD * 16, 256, 0, stream>>>(kws, xbf, tabp, kv, km);
    k3_out<<<16 * 64, 256, 0, stream>>>(qws, xbf, tabp, kv, km, lw, lb, out);
}